// Round 12
// baseline (43.141 us; speedup 1.0000x reference)
//
#include <hip/hip_runtime.h>

// FutureEncoder: out[b,t,:] = sum_j softmax_j(dot(x[b,t], x[b,t+1+j])) * x[b,t+1+j],
// j in [0,16), valid iff t+1+j < S. fp32 throughout.
//
// Round 12: two-phase burst design. Evidence: R6 (VALU serial, 26.3us),
// R11 (MFMA, 26.2us), R8/R10 (LDS-shared, 34-52us) all stall on dependency
// chains, none saturates a pipe. This kernel removes every serial structure:
//  Phase A: fragment-major -> 20 back-to-back dwordx4 loads per fragment
//           (20KB MLP/wave), 64 partial dots accumulated in registers.
//  Reduce:  ONE batched butterfly, 64 independent chains x 6 levels.
//  Softmax: exact (all scores on hand) - zero online-update branches.
//  Phase B: reload rows fragment-major (L2-hot burst), 4 FMA/row/t,
//           vector float4 stores.
// TPW=4: 5 rows/t -> hbm ~85MB -> 13.5us traffic bound. 2048 waves (2/SIMD)
// but ~10x the per-wave memory parallelism of the old serial TPW=4 (R3).

namespace {
constexpr int kB   = 2;
constexpr int kS   = 4096;
constexpr int kH   = 1024;
constexpr int kK   = 16;
constexpr int kTPW = 4;                   // t's per wave
constexpr int kRows = kTPW + kK;          // 20 rows: t0 .. t0+19
constexpr int kFR  = kH / (64 * 4);       // 4 float4 fragments per lane per row
constexpr int kWavesPerBlk = 4;           // 256 threads
constexpr int kBlocks = kB * kS / (kTPW * kWavesPerBlk);  // 512
constexpr int kXCD = 8;
}

__global__ __launch_bounds__(256, 2)
void future_encoder_kernel(const float* __restrict__ x, float* __restrict__ out) {
  const int lane = (int)(threadIdx.x & 63);
  const int wib  = (int)(threadIdx.x >> 6);

  // XCD strip swizzle (512 % 8 == 0 -> bijective): contiguous t-strips per XCD.
  const int vb  = (int)(blockIdx.x % kXCD) * (kBlocks / kXCD) + (int)(blockIdx.x / kXCD);
  const int tg  = (vb * kWavesPerBlk + wib) * kTPW;   // first t of this wave
  const int b   = tg / kS;
  const int t0  = tg % kS;                // 16 | 4096: block never crosses batches
  const float* __restrict__ xb = x   + (size_t)b * kS * kH;
  float* __restrict__       ob = out + (size_t)b * kS * kH;
  const int col = lane * 4;
  const int lim = (kS - 1) - t0;          // wave-uniform; rows beyond clamp to S-1

  // Row base pointers (wave-uniform except lane offset; clamped once).
  const float* rp[kRows];
#pragma unroll
  for (int i = 0; i < kRows; ++i) {
    const int ri = (i < lim) ? i : lim;
    rp[i] = xb + (size_t)(t0 + ri) * kH + col;
  }

  // ---- Phase A: all 64 partial dots, fragment-major burst loads ----
  float pd[kTPW][kK];
#pragma unroll
  for (int tt = 0; tt < kTPW; ++tt)
#pragma unroll
    for (int j = 0; j < kK; ++j) pd[tt][j] = 0.f;

#pragma unroll
  for (int p = 0; p < kFR; ++p) {
    float4 f[kRows];
#pragma unroll
    for (int i = 0; i < kRows; ++i)
      f[i] = *(const float4*)(rp[i] + p * 256);
#pragma unroll
    for (int tt = 0; tt < kTPW; ++tt)
#pragma unroll
      for (int j = 0; j < kK; ++j) {
        const float4 a = f[tt];
        const float4 g = f[tt + 1 + j];
        float s = pd[tt][j];
        s = fmaf(a.x, g.x, s);
        s = fmaf(a.y, g.y, s);
        s = fmaf(a.z, g.z, s);
        s = fmaf(a.w, g.w, s);
        pd[tt][j] = s;
      }
  }

  // ---- One batched butterfly: 64 independent chains per level ----
#pragma unroll
  for (int off = 32; off >= 1; off >>= 1) {
    float o[kTPW][kK];
#pragma unroll
    for (int tt = 0; tt < kTPW; ++tt)
#pragma unroll
      for (int j = 0; j < kK; ++j) o[tt][j] = __shfl_xor(pd[tt][j], off, 64);
#pragma unroll
    for (int tt = 0; tt < kTPW; ++tt)
#pragma unroll
      for (int j = 0; j < kK; ++j) pd[tt][j] += o[tt][j];
  }

  // ---- Exact softmax -> weights (wave-uniform; no online updates) ----
  float w[kTPW][kK];
#pragma unroll
  for (int tt = 0; tt < kTPW; ++tt) {
    float mx = -1e30f;
#pragma unroll
    for (int j = 0; j < kK; ++j) {
      const bool val = (tt + 1 + j) <= lim;
      const float sv = val ? pd[tt][j] : -1e30f;
      pd[tt][j] = sv;
      mx = fmaxf(mx, sv);
    }
    float sum = 0.f;
#pragma unroll
    for (int j = 0; j < kK; ++j) {
      const bool val = (tt + 1 + j) <= lim;
      const float e = val ? __expf(pd[tt][j] - mx) : 0.f;
      w[tt][j] = e;
      sum += e;
    }
    const float inv = (sum > 0.f) ? (1.f / sum) : 0.f;   // t==S-1 -> exact zeros
#pragma unroll
    for (int j = 0; j < kK; ++j) w[tt][j] *= inv;
  }

  // ---- Phase B: reload rows 1..19 fragment-major (L2-hot), weighted sum ----
#pragma unroll
  for (int p = 0; p < kFR; ++p) {
    float4 f[kRows - 1];
#pragma unroll
    for (int i = 1; i < kRows; ++i)
      f[i - 1] = *(const float4*)(rp[i] + p * 256);
#pragma unroll
    for (int tt = 0; tt < kTPW; ++tt) {
      float4 a = make_float4(0.f, 0.f, 0.f, 0.f);
#pragma unroll
      for (int j = 0; j < kK; ++j) {
        const float wt = w[tt][j];
        const float4 g = f[tt + j];          // row tt+1+j
        a.x = fmaf(wt, g.x, a.x);
        a.y = fmaf(wt, g.y, a.y);
        a.z = fmaf(wt, g.z, a.z);
        a.w = fmaf(wt, g.w, a.w);
      }
      *(float4*)(ob + (size_t)(t0 + tt) * kH + p * 256 + col) = a;
    }
  }
}

extern "C" void kernel_launch(void* const* d_in, const int* in_sizes, int n_in,
                              void* d_out, int out_size, void* d_ws, size_t ws_size,
                              hipStream_t stream) {
  const float* x = (const float*)d_in[0];
  float* out = (float*)d_out;
  hipLaunchKernelGGL(future_encoder_kernel, dim3(kBlocks), dim3(256), 0, stream,
                     x, out);
}

// Round 13
// 25.413 us; speedup vs baseline: 1.6976x; 1.6976x over previous
//
#include <hip/hip_runtime.h>

// FutureEncoder as banded flash-attention on MFMA (bf16 split-precision).
// out[b,t,:] = softmax_j(x[t]·x[t+1+j]) · x[t+1+j], j in [0,16), fp32 I/O.
//
// Round 13 = R11 + three dataflow fixes:
//  1) QK MFMA chain-split: 6 independent 4-deep chains (hi*hi/hi*lo/lo*hi
//     per K-tile) instead of two 12-deep serial chains -> MFMA pipelines.
//  2) V-gather prefetch: the 64 scalar V loads depend only on x; issue them
//     BEFORE the LDS-reduce barrier so their latency hides under the
//     reduce + softmax instead of serializing before PV.
//  3) s_setprio(1) around MFMA clusters (waves here are phase-diverse).

typedef float f32x4 __attribute__((ext_vector_type(4)));
typedef unsigned int u32;
typedef u32 u32x4 __attribute__((ext_vector_type(4)));
typedef short bf16x8 __attribute__((ext_vector_type(8)));

namespace {
constexpr int kB = 2, kS = 4096, kH = 1024;
constexpr int kWaves = 8;                    // 512 threads
constexpr int kTilesT = 16;                  // t's per block
constexpr int kBlocks = kB * kS / kTilesT;   // 512 -> 2 blocks/CU
constexpr int kXCD = 8;
constexpr int kHW = kH / kWaves;             // 128 h-cols per wave
}

__device__ __forceinline__ u32 f32u(float x){ return __builtin_bit_cast(u32, x); }
__device__ __forceinline__ float uf32(u32 x){ return __builtin_bit_cast(float, x); }
__device__ __forceinline__ u32 pkbf(float a, float b){ return (f32u(b)&0xFFFF0000u)|(f32u(a)>>16); }

struct Frag2 { bf16x8 hi, lo; };
__device__ __forceinline__ Frag2 split2(float4 u, float4 v) {
  float fu[8] = {u.x,u.y,u.z,u.w,v.x,v.y,v.z,v.w};
  u32 hw[4], lw[4];
#pragma unroll
  for (int i = 0; i < 4; ++i) {
    float a = fu[2*i], b = fu[2*i+1];
    u32 ua = f32u(a), ub = f32u(b);
    hw[i] = (ub & 0xFFFF0000u) | (ua >> 16);
    float la = a - uf32(ua & 0xFFFF0000u);
    float lb = b - uf32(ub & 0xFFFF0000u);
    lw[i] = (f32u(lb) & 0xFFFF0000u) | (f32u(la) >> 16);
  }
  Frag2 r;
  u32x4 h = {hw[0],hw[1],hw[2],hw[3]}, l = {lw[0],lw[1],lw[2],lw[3]};
  r.hi = __builtin_bit_cast(bf16x8, h);
  r.lo = __builtin_bit_cast(bf16x8, l);
  return r;
}

#define MFMA(A,B,C) __builtin_amdgcn_mfma_f32_16x16x32_bf16((A),(B),(C),0,0,0)

__global__ __launch_bounds__(512, 4)
void fenc_mfma(const float* __restrict__ x, float* __restrict__ out) {
  __shared__ float red[kWaves][2][4][64];   // 16 KB: per-wave S^T partials
  const int lane = (int)(threadIdx.x & 63), wid = (int)(threadIdx.x >> 6);
  const int g = lane >> 4, c = lane & 15;

  // XCD strip swizzle (512 % 8 == 0 -> bijective)
  const int vb  = (int)(blockIdx.x % kXCD)*(kBlocks/kXCD) + (int)(blockIdx.x / kXCD);
  const int t0g = vb * kTilesT;
  const int b   = t0g / kS, t0 = t0g % kS;
  const float* __restrict__ xb = x + (size_t)b*kS*kH;
  float* __restrict__ ob = out + (size_t)b*kS*kH;
  const int hw0 = kHW * wid;

  // ---- QK^T (swapped: A = K windows, B = Q), k-split over H ----
  const int ra = (t0 + 1 + c  < kS) ? (t0 + 1 + c)  : (kS - 1);
  const int rb = (t0 + 17 + c < kS) ? (t0 + 17 + c) : (kS - 1);
  const float* qp  = xb + (size_t)(t0 + c)*kH + hw0;
  const float* kpa = xb + (size_t)ra*kH + hw0;
  const float* kpb = xb + (size_t)rb*kH + hw0;

  // 6 independent accumulation chains (depth 4 each) -> MFMA pipelines.
  f32x4 aHH = {0.f,0.f,0.f,0.f}, aHL = aHH, aLH = aHH;
  f32x4 bHH = aHH, bHL = aHH, bLH = aHH;
  __builtin_amdgcn_s_setprio(1);
#pragma unroll
  for (int ks = 0; ks < 4; ++ks) {
    const int off = ks*32 + g*8;
    float4 q0 = *(const float4*)(qp  + off), q1 = *(const float4*)(qp  + off + 4);
    float4 a0 = *(const float4*)(kpa + off), a1 = *(const float4*)(kpa + off + 4);
    float4 b0 = *(const float4*)(kpb + off), b1 = *(const float4*)(kpb + off + 4);
    Frag2 fq = split2(q0, q1), fa = split2(a0, a1), fb = split2(b0, b1);
    aHH = MFMA(fa.hi, fq.hi, aHH);
    aHL = MFMA(fa.hi, fq.lo, aHL);
    aLH = MFMA(fa.lo, fq.hi, aLH);
    bHH = MFMA(fb.hi, fq.hi, bHH);
    bHL = MFMA(fb.hi, fq.lo, bHL);
    bLH = MFMA(fb.lo, fq.hi, bLH);
  }
  __builtin_amdgcn_s_setprio(0);
  f32x4 accA = (aHH + aHL) + aLH;
  f32x4 accB = (bHH + bHL) + bLH;

  // ---- V-gather PREFETCH: depends only on x; issue before the barrier so
  // the 64 scalar loads complete under the LDS reduce + softmax. ----
  const float* vrow[8];
#pragma unroll
  for (int i = 0; i < 8; ++i) {
    const int rv = t0 + 1 + 8*g + i;
    vrow[i] = xb + (size_t)((rv < kS) ? rv : (kS - 1))*kH + hw0 + c;
  }
  float vf[8][8];
#pragma unroll
  for (int nt = 0; nt < 8; ++nt)
#pragma unroll
    for (int i = 0; i < 8; ++i) vf[nt][i] = vrow[i][16*nt];

  // ---- cross-wave reduce of S^T partials (lane-linear, conflict-free) ----
#pragma unroll
  for (int r = 0; r < 4; ++r) {
    red[wid][0][r][lane] = accA[r];
    red[wid][1][r][lane] = accB[r];
  }
  __syncthreads();
#pragma unroll
  for (int w = 0; w < kWaves; ++w) {
    if (w != wid) {
#pragma unroll
      for (int r = 0; r < 4; ++r) {
        accA[r] += red[w][0][r][lane];
        accB[r] += red[w][1][r][lane];
      }
    }
  }

  // ---- softmax (per lane: all 32 windows of t = t0+c live in accA/accB) ----
  float p[2][4];
  float vmax = -1e30f;
#pragma unroll
  for (int T = 0; T < 2; ++T)
#pragma unroll
    for (int r = 0; r < 4; ++r) {
      const int w = 16*T + 4*g + r;
      const bool val = (w >= c) && (w < c + 16) && (t0 + 1 + w < kS);
      const float sv = val ? (T ? accB[r] : accA[r]) : -1e30f;
      p[T][r] = sv;
      vmax = fmaxf(vmax, sv);
    }
  vmax = fmaxf(vmax, __shfl_xor(vmax, 16, 64));
  vmax = fmaxf(vmax, __shfl_xor(vmax, 32, 64));
  float psum = 0.f;
#pragma unroll
  for (int T = 0; T < 2; ++T)
#pragma unroll
    for (int r = 0; r < 4; ++r) {
      const int w = 16*T + 4*g + r;
      const bool val = (w >= c) && (w < c + 16) && (t0 + 1 + w < kS);
      const float e = val ? __expf(p[T][r] - vmax) : 0.f;
      p[T][r] = e;
      psum += e;
    }
  psum += __shfl_xor(psum, 16, 64);
  psum += __shfl_xor(psum, 32, 64);
  const float inv = (psum > 0.f) ? (1.f / psum) : 0.f;
#pragma unroll
  for (int T = 0; T < 2; ++T)
#pragma unroll
    for (int r = 0; r < 4; ++r) p[T][r] *= inv;

  // ---- build P^T A-frag: lane needs P[t=c][w = 8g+i], i=0..7 ----
  const int se = (g & 1)*32 + c, so = se + 16;
  float slot[8];
#pragma unroll
  for (int r = 0; r < 4; ++r) {
    const float e0 = __shfl(p[0][r], se, 64), e1 = __shfl(p[1][r], se, 64);
    const float o0 = __shfl(p[0][r], so, 64), o1 = __shfl(p[1][r], so, 64);
    slot[r]     = (g >> 1) ? e1 : e0;
    slot[4 + r] = (g >> 1) ? o1 : o0;
  }
  u32x4 pw = { pkbf(slot[0],slot[1]), pkbf(slot[2],slot[3]),
               pkbf(slot[4],slot[5]), pkbf(slot[6],slot[7]) };
  const bf16x8 pa = __builtin_bit_cast(bf16x8, pw);

  // ---- PV: O[t][h] = sum_w P[t][w] V[w][h]; V already in registers ----
  f32x4 o[8];
  __builtin_amdgcn_s_setprio(1);
#pragma unroll
  for (int nt = 0; nt < 8; ++nt) {
    u32x4 vw = { pkbf(vf[nt][0],vf[nt][1]), pkbf(vf[nt][2],vf[nt][3]),
                 pkbf(vf[nt][4],vf[nt][5]), pkbf(vf[nt][6],vf[nt][7]) };
    const bf16x8 vfrag = __builtin_bit_cast(bf16x8, vw);
    f32x4 z = {0.f,0.f,0.f,0.f};
    o[nt] = MFMA(pa, vfrag, z);
  }
  __builtin_amdgcn_s_setprio(0);

  // ---- store: C/D layout -> O[t = t0+4g+r][h = hw0 + 16nt + c] ----
  float* orow[4];
#pragma unroll
  for (int r = 0; r < 4; ++r)
    orow[r] = ob + (size_t)(t0 + 4*g + r)*kH + hw0 + c;
#pragma unroll
  for (int nt = 0; nt < 8; ++nt)
#pragma unroll
    for (int r = 0; r < 4; ++r)
      orow[r][16*nt] = o[nt][r];
}

extern "C" void kernel_launch(void* const* d_in, const int* in_sizes, int n_in,
                              void* d_out, int out_size, void* d_ws, size_t ws_size,
                              hipStream_t stream) {
  const float* x = (const float*)d_in[0];
  float* out = (float*)d_out;
  hipLaunchKernelGGL(fenc_mfma, dim3(kBlocks), dim3(512), 0, stream, x, out);
}